// Round 1
// baseline (220.921 us; speedup 1.0000x reference)
//
#include <hip/hip_runtime.h>

#define L_LEN 8192
#define H_DIM 512
#define P_DIM 256
#define CHUNKS 64
#define CLEN (L_LEN / CHUNKS)

// ---- workspace layout (float offsets) ----
#define OFF_BBRE   0
#define OFF_BBIM   (OFF_BBRE + P_DIM * H_DIM)
#define OFF_CRE    (OFF_BBIM + P_DIM * H_DIM)
#define OFF_CIM    (OFF_CRE  + H_DIM * P_DIM)
#define OFF_LBRE   (OFF_CIM  + H_DIM * P_DIM)
#define OFF_LBIM   (OFF_LBRE + P_DIM)
#define OFF_BURE   (OFF_LBIM + P_DIM)
#define OFF_BUIM   (OFF_BURE + L_LEN * P_DIM)
#define OFF_XSRE   (OFF_BUIM + L_LEN * P_DIM)
#define OFF_XSIM   (OFF_XSRE + L_LEN * P_DIM)
#define OFF_AGAR   (OFF_XSIM + L_LEN * P_DIM)
#define OFF_AGAI   (OFF_AGAR + CHUNKS * P_DIM)
#define OFF_AGBR   (OFF_AGAI + CHUNKS * P_DIM)
#define OFF_AGBI   (OFF_AGBR + CHUNKS * P_DIM)
#define OFF_AGC    (OFF_AGBI + CHUNKS * P_DIM)
#define OFF_CARR   (OFF_AGC  + CHUNKS)
#define OFF_CARI   (OFF_CARR + CHUNKS * P_DIM)

// ---------------------------------------------------------------------------
// K0: precompute Lambda_bar (P complex), B_bar (P,H complex), split C planes
// ---------------------------------------------------------------------------
__global__ __launch_bounds__(256) void s5_k0_pre(
    const float* __restrict__ Lre, const float* __restrict__ Lim,
    const float* __restrict__ logstep,
    const float* __restrict__ B,   // (P,H,2)
    const float* __restrict__ C,   // (H,P,2)
    float* __restrict__ Bbre, float* __restrict__ Bbim,
    float* __restrict__ Cre,  float* __restrict__ Cim,
    float* __restrict__ Lbre, float* __restrict__ Lbim)
{
    int idx = blockIdx.x * blockDim.x + threadIdx.x;
    if (idx >= P_DIM * H_DIM) return;

    // C split: idx runs over flattened (H,P)
    Cre[idx] = C[2 * idx + 0];
    Cim[idx] = C[2 * idx + 1];

    int p = idx / H_DIM;
    int h = idx - p * H_DIM;
    float lre = Lre[p], lim = Lim[p];
    float s = expf(logstep[p]);
    float er = expf(lre * s);
    float lbr = er * cosf(lim * s);
    float lbi = er * sinf(lim * s);
    if (h == 0) { Lbre[p] = lbr; Lbim[p] = lbi; }
    // f = (Lambda_bar - 1) / Lambda
    float nr = lbr - 1.0f, ni = lbi;
    float d = lre * lre + lim * lim;
    float inv = 1.0f / d;
    float fr = (nr * lre + ni * lim) * inv;
    float fi = (ni * lre - nr * lim) * inv;
    float b0 = B[2 * (p * H_DIM + h) + 0];
    float b1 = B[2 * (p * H_DIM + h) + 1];
    Bbre[p * H_DIM + h] = fr * b0 - fi * b1;
    Bbim[p * H_DIM + h] = fr * b1 + fi * b0;
}

// ---------------------------------------------------------------------------
// K1: Bu[L,P] = u[L,H] @ B_bar[P,H]^T  (re and im planes)
// 64x64 tile, 256 threads, 4x4 micro-tile per thread, K-step 16
// ---------------------------------------------------------------------------
__global__ __launch_bounds__(256) void s5_k1_bu(
    const float* __restrict__ u,
    const float* __restrict__ Bbre, const float* __restrict__ Bbim,
    float* __restrict__ Bure, float* __restrict__ Buim)
{
    __shared__ float su [64][17];
    __shared__ float sbr[64][17];
    __shared__ float sbi[64][17];

    const int tid = threadIdx.x;
    const int rowBase = blockIdx.y * 64;   // L rows
    const int colBase = blockIdx.x * 64;   // P cols
    const int tr = tid >> 4, tc = tid & 15;
    const int lrow = tid >> 2, lq = (tid & 3) * 4;

    float accre[4][4] = {{0.f}}, accim[4][4] = {{0.f}};

    for (int kk = 0; kk < H_DIM; kk += 16) {
        float4 uv  = *(const float4*)(u    + (size_t)(rowBase + lrow) * H_DIM + kk + lq);
        float4 brv = *(const float4*)(Bbre + (size_t)(colBase + lrow) * H_DIM + kk + lq);
        float4 biv = *(const float4*)(Bbim + (size_t)(colBase + lrow) * H_DIM + kk + lq);
        su [lrow][lq+0] = uv.x;  su [lrow][lq+1] = uv.y;  su [lrow][lq+2] = uv.z;  su [lrow][lq+3] = uv.w;
        sbr[lrow][lq+0] = brv.x; sbr[lrow][lq+1] = brv.y; sbr[lrow][lq+2] = brv.z; sbr[lrow][lq+3] = brv.w;
        sbi[lrow][lq+0] = biv.x; sbi[lrow][lq+1] = biv.y; sbi[lrow][lq+2] = biv.z; sbi[lrow][lq+3] = biv.w;
        __syncthreads();
        #pragma unroll
        for (int k = 0; k < 16; ++k) {
            float a[4], br[4], bi[4];
            #pragma unroll
            for (int i = 0; i < 4; ++i) a[i] = su[tr + 16 * i][k];
            #pragma unroll
            for (int j = 0; j < 4; ++j) { br[j] = sbr[tc + 16 * j][k]; bi[j] = sbi[tc + 16 * j][k]; }
            #pragma unroll
            for (int i = 0; i < 4; ++i)
                #pragma unroll
                for (int j = 0; j < 4; ++j) {
                    accre[i][j] = fmaf(a[i], br[j], accre[i][j]);
                    accim[i][j] = fmaf(a[i], bi[j], accim[i][j]);
                }
        }
        __syncthreads();
    }

    #pragma unroll
    for (int i = 0; i < 4; ++i) {
        int r = rowBase + tr + 16 * i;
        #pragma unroll
        for (int j = 0; j < 4; ++j) {
            int c = colBase + tc + 16 * j;
            Bure[(size_t)r * P_DIM + c] = accre[i][j];
            Buim[(size_t)r * P_DIM + c] = accim[i][j];
        }
    }
}

// ---------------------------------------------------------------------------
// K2: per-chunk aggregates (A_agg, b_agg, c_agg) via sequential operator
// grid = CHUNKS blocks, blockDim = P (thread = channel p)
// ---------------------------------------------------------------------------
__global__ __launch_bounds__(P_DIM) void s5_k2_agg(
    const float* __restrict__ Bure, const float* __restrict__ Buim,
    const int* __restrict__ resets,
    const float* __restrict__ Lbre, const float* __restrict__ Lbim,
    float* __restrict__ aAr, float* __restrict__ aAi,
    float* __restrict__ aBr, float* __restrict__ aBi,
    float* __restrict__ aC)
{
    const int p = threadIdx.x;
    const int ci = blockIdx.x;
    const float lbr = Lbre[p], lbi = Lbim[p];
    float Ar = 1.f, Ai = 0.f, br = 0.f, bi = 0.f;
    int c = 0;
    const int t0 = ci * CLEN;
    for (int t = t0; t < t0 + CLEN; ++t) {
        int r = resets[t];
        float bur = Bure[(size_t)t * P_DIM + p];
        float bui = Buim[(size_t)t * P_DIM + p];
        if (r) {
            Ar = lbr; Ai = lbi; br = bur; bi = bui; c = 1;
        } else {
            float nAr = lbr * Ar - lbi * Ai;
            Ai = lbr * Ai + lbi * Ar; Ar = nAr;
            float nbr = lbr * br - lbi * bi + bur;
            bi = lbr * bi + lbi * br + bui; br = nbr;
        }
    }
    aAr[ci * P_DIM + p] = Ar; aAi[ci * P_DIM + p] = Ai;
    aBr[ci * P_DIM + p] = br; aBi[ci * P_DIM + p] = bi;
    if (p == 0) aC[ci] = (float)c;
}

// ---------------------------------------------------------------------------
// K3: sequential combine over chunk aggregates -> carry-in per chunk
// 1 block, thread = p
// ---------------------------------------------------------------------------
__global__ __launch_bounds__(P_DIM) void s5_k3_combine(
    const float* __restrict__ hidden,
    const float* __restrict__ aAr, const float* __restrict__ aAi,
    const float* __restrict__ aBr, const float* __restrict__ aBi,
    const float* __restrict__ aC,
    float* __restrict__ carR, float* __restrict__ carI)
{
    const int p = threadIdx.x;
    float sr = hidden[p], si = 0.f;
    for (int ci = 0; ci < CHUNKS; ++ci) {
        carR[ci * P_DIM + p] = sr;
        carI[ci * P_DIM + p] = si;
        float Ar = aAr[ci * P_DIM + p], Ai = aAi[ci * P_DIM + p];
        float br = aBr[ci * P_DIM + p], bi = aBi[ci * P_DIM + p];
        if (aC[ci] > 0.5f) {
            sr = br; si = bi;
        } else {
            float t = Ar * sr - Ai * si + br;
            si = Ar * si + Ai * sr + bi;
            sr = t;
        }
    }
}

// ---------------------------------------------------------------------------
// K4: re-scan each chunk with carry-in, write xs
// ---------------------------------------------------------------------------
__global__ __launch_bounds__(P_DIM) void s5_k4_scan(
    const float* __restrict__ Bure, const float* __restrict__ Buim,
    const int* __restrict__ resets,
    const float* __restrict__ Lbre, const float* __restrict__ Lbim,
    const float* __restrict__ carR, const float* __restrict__ carI,
    float* __restrict__ xsre, float* __restrict__ xsim)
{
    const int p = threadIdx.x;
    const int ci = blockIdx.x;
    const float lbr = Lbre[p], lbi = Lbim[p];
    float sr = carR[ci * P_DIM + p];
    float si = carI[ci * P_DIM + p];
    const int t0 = ci * CLEN;
    for (int t = t0; t < t0 + CLEN; ++t) {
        int r = resets[t];
        float bur = Bure[(size_t)t * P_DIM + p];
        float bui = Buim[(size_t)t * P_DIM + p];
        if (r) {
            sr = bur; si = bui;
        } else {
            float nr = lbr * sr - lbi * si + bur;
            si = lbr * si + lbi * sr + bui;
            sr = nr;
        }
        xsre[(size_t)t * P_DIM + p] = sr;
        xsim[(size_t)t * P_DIM + p] = si;
    }
}

// ---------------------------------------------------------------------------
// K5: out[L,H] = 2*(xs_re @ Cre^T - xs_im @ Cim^T) + u * D
// 64x64 tile, 256 threads, 4x4 micro-tile per thread, K-step 16 (K = P = 256)
// ---------------------------------------------------------------------------
__global__ __launch_bounds__(256) void s5_k5_out(
    const float* __restrict__ xsre, const float* __restrict__ xsim,
    const float* __restrict__ Cre,  const float* __restrict__ Cim,
    const float* __restrict__ u,    const float* __restrict__ D,
    float* __restrict__ out)
{
    __shared__ float sxr[64][17];
    __shared__ float sxi[64][17];
    __shared__ float scr[64][17];
    __shared__ float sci[64][17];

    const int tid = threadIdx.x;
    const int rowBase = blockIdx.y * 64;   // L rows
    const int hBase   = blockIdx.x * 64;   // H cols
    const int tr = tid >> 4, tc = tid & 15;
    const int lrow = tid >> 2, lq = (tid & 3) * 4;

    float acc[4][4] = {{0.f}};

    for (int kk = 0; kk < P_DIM; kk += 16) {
        float4 xr = *(const float4*)(xsre + (size_t)(rowBase + lrow) * P_DIM + kk + lq);
        float4 xi = *(const float4*)(xsim + (size_t)(rowBase + lrow) * P_DIM + kk + lq);
        float4 cr = *(const float4*)(Cre  + (size_t)(hBase   + lrow) * P_DIM + kk + lq);
        float4 ci = *(const float4*)(Cim  + (size_t)(hBase   + lrow) * P_DIM + kk + lq);
        sxr[lrow][lq+0] = xr.x; sxr[lrow][lq+1] = xr.y; sxr[lrow][lq+2] = xr.z; sxr[lrow][lq+3] = xr.w;
        sxi[lrow][lq+0] = xi.x; sxi[lrow][lq+1] = xi.y; sxi[lrow][lq+2] = xi.z; sxi[lrow][lq+3] = xi.w;
        scr[lrow][lq+0] = cr.x; scr[lrow][lq+1] = cr.y; scr[lrow][lq+2] = cr.z; scr[lrow][lq+3] = cr.w;
        sci[lrow][lq+0] = ci.x; sci[lrow][lq+1] = ci.y; sci[lrow][lq+2] = ci.z; sci[lrow][lq+3] = ci.w;
        __syncthreads();
        #pragma unroll
        for (int k = 0; k < 16; ++k) {
            float ar[4], ai[4], br[4], bi[4];
            #pragma unroll
            for (int i = 0; i < 4; ++i) { ar[i] = sxr[tr + 16 * i][k]; ai[i] = sxi[tr + 16 * i][k]; }
            #pragma unroll
            for (int j = 0; j < 4; ++j) { br[j] = scr[tc + 16 * j][k]; bi[j] = sci[tc + 16 * j][k]; }
            #pragma unroll
            for (int i = 0; i < 4; ++i)
                #pragma unroll
                for (int j = 0; j < 4; ++j) {
                    acc[i][j] = fmaf(ar[i], br[j], acc[i][j]);
                    acc[i][j] = fmaf(-ai[i], bi[j], acc[i][j]);
                }
        }
        __syncthreads();
    }

    float Dj[4];
    #pragma unroll
    for (int j = 0; j < 4; ++j) Dj[j] = D[hBase + tc + 16 * j];

    #pragma unroll
    for (int i = 0; i < 4; ++i) {
        int r = rowBase + tr + 16 * i;
        #pragma unroll
        for (int j = 0; j < 4; ++j) {
            int c = hBase + tc + 16 * j;
            out[(size_t)r * H_DIM + c] = 2.0f * acc[i][j] + u[(size_t)r * H_DIM + c] * Dj[j];
        }
    }
}

// ---------------------------------------------------------------------------
extern "C" void kernel_launch(void* const* d_in, const int* in_sizes, int n_in,
                              void* d_out, int out_size, void* d_ws, size_t ws_size,
                              hipStream_t stream)
{
    const float* hidden  = (const float*)d_in[0];
    const float* u       = (const float*)d_in[1];
    const float* Lre     = (const float*)d_in[2];
    const float* Lim     = (const float*)d_in[3];
    const float* B       = (const float*)d_in[4];
    const float* C       = (const float*)d_in[5];
    const float* D       = (const float*)d_in[6];
    const float* logstep = (const float*)d_in[7];
    const int*   resets  = (const int*)d_in[8];
    float* out = (float*)d_out;
    float* ws  = (float*)d_ws;

    s5_k0_pre<<<(P_DIM * H_DIM + 255) / 256, 256, 0, stream>>>(
        Lre, Lim, logstep, B, C,
        ws + OFF_BBRE, ws + OFF_BBIM, ws + OFF_CRE, ws + OFF_CIM,
        ws + OFF_LBRE, ws + OFF_LBIM);

    s5_k1_bu<<<dim3(P_DIM / 64, L_LEN / 64), 256, 0, stream>>>(
        u, ws + OFF_BBRE, ws + OFF_BBIM, ws + OFF_BURE, ws + OFF_BUIM);

    s5_k2_agg<<<CHUNKS, P_DIM, 0, stream>>>(
        ws + OFF_BURE, ws + OFF_BUIM, resets, ws + OFF_LBRE, ws + OFF_LBIM,
        ws + OFF_AGAR, ws + OFF_AGAI, ws + OFF_AGBR, ws + OFF_AGBI, ws + OFF_AGC);

    s5_k3_combine<<<1, P_DIM, 0, stream>>>(
        hidden, ws + OFF_AGAR, ws + OFF_AGAI, ws + OFF_AGBR, ws + OFF_AGBI,
        ws + OFF_AGC, ws + OFF_CARR, ws + OFF_CARI);

    s5_k4_scan<<<CHUNKS, P_DIM, 0, stream>>>(
        ws + OFF_BURE, ws + OFF_BUIM, resets, ws + OFF_LBRE, ws + OFF_LBIM,
        ws + OFF_CARR, ws + OFF_CARI, ws + OFF_XSRE, ws + OFF_XSIM);

    s5_k5_out<<<dim3(H_DIM / 64, L_LEN / 64), 256, 0, stream>>>(
        ws + OFF_XSRE, ws + OFF_XSIM, ws + OFF_CRE, ws + OFF_CIM,
        u, D, out);
}

// Round 3
// 130.714 us; speedup vs baseline: 1.6901x; 1.6901x over previous
//
#include <hip/hip_runtime.h>

#define L_LEN 8192
#define H_DIM 512
#define P_DIM 256
#define N2P   512
#define CHUNKS 512
#define CLEN  (L_LEN / CHUNKS)

typedef short bf16x8 __attribute__((ext_vector_type(8)));
typedef float f32x4  __attribute__((ext_vector_type(4)));

// ---- workspace layout (FLOAT offsets; bf16 buffers sized as shorts/2) ----
#define OFF_BMT   0                          // bf16 [512][512] -> 131072 floats
#define OFF_W2T   (OFF_BMT + 131072)         // bf16 [512][512] -> 131072 floats
#define OFF_LBRE  (OFF_W2T + 131072)
#define OFF_LBIM  (OFF_LBRE + 256)
#define OFF_BU    (OFF_LBIM + 256)           // fp32 [L][512]
#define OFF_XC    (OFF_BU + L_LEN * 512)     // bf16 [L][512] -> L*256 floats
#define OFF_AGAR  (OFF_XC + L_LEN * 256)
#define OFF_AGAI  (OFF_AGAR + CHUNKS * P_DIM)
#define OFF_AGBR  (OFF_AGAI + CHUNKS * P_DIM)
#define OFF_AGBI  (OFF_AGBR + CHUNKS * P_DIM)
#define OFF_AGC   (OFF_AGBI + CHUNKS * P_DIM)
#define OFF_CARR  (OFF_AGC  + CHUNKS)
#define OFF_CARI  (OFF_CARR + CHUNKS * P_DIM)

__device__ __forceinline__ unsigned short bfr(float x) {
    unsigned u = __float_as_uint(x);
    u = (u + 0x7fffu + ((u >> 16) & 1u)) >> 16;
    return (unsigned short)u;
}
__device__ __forceinline__ unsigned pk(float a, float b) {
    return (unsigned)bfr(a) | ((unsigned)bfr(b) << 16);
}

// ---------------------------------------------------------------------------
// K0: precompute Lambda_bar, BmT (bf16, [2P][H]), W2T (bf16, [H][2P] interleaved)
// ---------------------------------------------------------------------------
__global__ __launch_bounds__(256) void s5_k0(
    const float* __restrict__ Lre, const float* __restrict__ Lim,
    const float* __restrict__ logstep,
    const float* __restrict__ B,   // (P,H,2)
    const float* __restrict__ C,   // (H,P,2)
    short* __restrict__ BmT, unsigned* __restrict__ W2Tu,
    float* __restrict__ Lbre, float* __restrict__ Lbim)
{
    int idx = blockIdx.x * 256 + threadIdx.x;   // 0 .. 131071

    // ---- B_bar part: idx -> (p, h) ----
    int p = idx >> 9, h = idx & 511;
    float lre = Lre[p], lim = Lim[p];
    float s = expf(logstep[p]);
    float er = expf(lre * s);
    float lbr = er * cosf(lim * s);
    float lbi = er * sinf(lim * s);
    if (h == 0) { Lbre[p] = lbr; Lbim[p] = lbi; }
    float nr = lbr - 1.0f, ni = lbi;
    float inv = 1.0f / (lre * lre + lim * lim);
    float fr = (nr * lre + ni * lim) * inv;
    float fi = (ni * lre - nr * lim) * inv;
    float b0 = B[2 * idx + 0];
    float b1 = B[2 * idx + 1];
    BmT[(size_t)p * 512 + h]         = (short)bfr(fr * b0 - fi * b1);
    BmT[(size_t)(256 + p) * 512 + h] = (short)bfr(fr * b1 + fi * b0);

    // ---- C part: idx -> (hh, pp) ----
    int hh = idx >> 8, pp = idx & 255;
    float cre = C[2 * idx + 0];
    float cim = C[2 * idx + 1];
    W2Tu[(size_t)hh * 256 + pp] = pk(2.0f * cre, -2.0f * cim);
}

// ---------------------------------------------------------------------------
// bf16 MFMA GEMM: Out[M=8192][N] = A[M][512] @ WT[N][512]^T (WT row-major [n][k])
// BM=BN=BK=64, 256 threads (4 waves, 2x2), double-buffered padded LDS
// ---------------------------------------------------------------------------
template<bool AFP32, bool EPI>
__global__ __launch_bounds__(256) void s5_gemm(
    const void* __restrict__ Ap, const short* __restrict__ WT,
    const float* __restrict__ u, const float* __restrict__ Dv,
    float* __restrict__ Out)
{
    __shared__ __align__(16) short lds[2][2][64][72];

    const int tid = threadIdx.x;
    const int rowBase = blockIdx.y * 64;
    const int colBase = blockIdx.x * 64;
    const int srow = tid >> 2;
    const int scq  = (tid & 3) * 16;

    const int w = tid >> 6, l = tid & 63;
    const int wr = (w >> 1) * 32, wc = (w & 1) * 32;
    const int fr = l & 15, fq = l >> 4;

    int4 ra0, ra1, rb0, rb1;

    auto LOAD = [&](int t) {
        const int kk = t * 64;
        if (AFP32) {
            const float* A = (const float*)Ap;
            const float4* sa = (const float4*)(A + (size_t)(rowBase + srow) * 512 + kk + scq);
            float4 f0 = sa[0], f1 = sa[1], f2 = sa[2], f3 = sa[3];
            ra0 = make_int4((int)pk(f0.x,f0.y), (int)pk(f0.z,f0.w), (int)pk(f1.x,f1.y), (int)pk(f1.z,f1.w));
            ra1 = make_int4((int)pk(f2.x,f2.y), (int)pk(f2.z,f2.w), (int)pk(f3.x,f3.y), (int)pk(f3.z,f3.w));
        } else {
            const short* A = (const short*)Ap;
            const int4* sa = (const int4*)(A + (size_t)(rowBase + srow) * 512 + kk + scq);
            ra0 = sa[0]; ra1 = sa[1];
        }
        const int4* sb = (const int4*)(WT + (size_t)(colBase + srow) * 512 + kk + scq);
        rb0 = sb[0]; rb1 = sb[1];
    };
    auto WRITE = [&](int buf) {
        *(int4*)&lds[buf][0][srow][scq]     = ra0;
        *(int4*)&lds[buf][0][srow][scq + 8] = ra1;
        *(int4*)&lds[buf][1][srow][scq]     = rb0;
        *(int4*)&lds[buf][1][srow][scq + 8] = rb1;
    };

    f32x4 acc[2][2] = {};

    auto COMPUTE = [&](int buf) {
        #pragma unroll
        for (int kc = 0; kc < 2; ++kc) {
            bf16x8 a0 = *(const bf16x8*)&lds[buf][0][wr +      fr][kc * 32 + 8 * fq];
            bf16x8 a1 = *(const bf16x8*)&lds[buf][0][wr + 16 + fr][kc * 32 + 8 * fq];
            bf16x8 b0 = *(const bf16x8*)&lds[buf][1][wc +      fr][kc * 32 + 8 * fq];
            bf16x8 b1 = *(const bf16x8*)&lds[buf][1][wc + 16 + fr][kc * 32 + 8 * fq];
            acc[0][0] = __builtin_amdgcn_mfma_f32_16x16x32_bf16(a0, b0, acc[0][0], 0, 0, 0);
            acc[0][1] = __builtin_amdgcn_mfma_f32_16x16x32_bf16(a0, b1, acc[0][1], 0, 0, 0);
            acc[1][0] = __builtin_amdgcn_mfma_f32_16x16x32_bf16(a1, b0, acc[1][0], 0, 0, 0);
            acc[1][1] = __builtin_amdgcn_mfma_f32_16x16x32_bf16(a1, b1, acc[1][1], 0, 0, 0);
        }
    };

    LOAD(0); WRITE(0); __syncthreads();
    #pragma unroll
    for (int t = 0; t < 8; ++t) {
        if (t + 1 < 8) LOAD(t + 1);
        COMPUTE(t & 1);
        if (t + 1 < 8) WRITE((t + 1) & 1);
        __syncthreads();
    }

    float dv0 = 0.f, dv1 = 0.f;
    if (EPI) { dv0 = Dv[colBase + wc + fr]; dv1 = Dv[colBase + wc + 16 + fr]; }

    #pragma unroll
    for (int i = 0; i < 2; ++i)
        #pragma unroll
        for (int j = 0; j < 2; ++j)
            #pragma unroll
            for (int q = 0; q < 4; ++q) {
                int r = rowBase + wr + 16 * i + fq * 4 + q;
                int c = colBase + wc + 16 * j + fr;
                float v = acc[i][j][q];
                if (EPI) v += u[(size_t)r * 512 + c] * (j ? dv1 : dv0);
                Out[(size_t)r * 512 + c] = v;
            }
}

// ---------------------------------------------------------------------------
// K2: per-chunk aggregates
// ---------------------------------------------------------------------------
__global__ __launch_bounds__(P_DIM) void s5_k2(
    const float* __restrict__ Bu, const int* __restrict__ resets,
    const float* __restrict__ Lbre, const float* __restrict__ Lbim,
    float* __restrict__ aAr, float* __restrict__ aAi,
    float* __restrict__ aBr, float* __restrict__ aBi, float* __restrict__ aC)
{
    const int p = threadIdx.x, ci = blockIdx.x;
    const float lbr = Lbre[p], lbi = Lbim[p];
    float Ar = 1.f, Ai = 0.f, br = 0.f, bi = 0.f;
    int c = 0;
    const int t0 = ci * CLEN;
    for (int t = t0; t < t0 + CLEN; ++t) {
        int rs = resets[t];
        float bur = Bu[(size_t)t * 512 + p];
        float bui = Bu[(size_t)t * 512 + 256 + p];
        if (rs) { Ar = lbr; Ai = lbi; br = bur; bi = bui; c = 1; }
        else {
            float nAr = lbr * Ar - lbi * Ai; Ai = lbr * Ai + lbi * Ar; Ar = nAr;
            float nbr = lbr * br - lbi * bi + bur; bi = lbr * bi + lbi * br + bui; br = nbr;
        }
    }
    aAr[ci * P_DIM + p] = Ar; aAi[ci * P_DIM + p] = Ai;
    aBr[ci * P_DIM + p] = br; aBi[ci * P_DIM + p] = bi;
    if (p == 0) aC[ci] = (float)c;
}

// ---------------------------------------------------------------------------
// K3: sequential combine -> carry-in per chunk
// ---------------------------------------------------------------------------
__global__ __launch_bounds__(P_DIM) void s5_k3(
    const float* __restrict__ hidden,
    const float* __restrict__ aAr, const float* __restrict__ aAi,
    const float* __restrict__ aBr, const float* __restrict__ aBi,
    const float* __restrict__ aC,
    float* __restrict__ carR, float* __restrict__ carI)
{
    const int p = threadIdx.x;
    float sr = hidden[p], si = 0.f;
    for (int ci = 0; ci < CHUNKS; ++ci) {
        carR[ci * P_DIM + p] = sr;
        carI[ci * P_DIM + p] = si;
        float Ar = aAr[ci * P_DIM + p], Ai = aAi[ci * P_DIM + p];
        float br = aBr[ci * P_DIM + p], bi = aBi[ci * P_DIM + p];
        if (aC[ci] > 0.5f) { sr = br; si = bi; }
        else {
            float t = Ar * sr - Ai * si + br;
            si = Ar * si + Ai * sr + bi;
            sr = t;
        }
    }
}

// ---------------------------------------------------------------------------
// K4: re-scan with carry, write xs as packed bf16 (re,im) per p
// ---------------------------------------------------------------------------
__global__ __launch_bounds__(P_DIM) void s5_k4(
    const float* __restrict__ Bu, const int* __restrict__ resets,
    const float* __restrict__ Lbre, const float* __restrict__ Lbim,
    const float* __restrict__ carR, const float* __restrict__ carI,
    unsigned* __restrict__ xcu)
{
    const int p = threadIdx.x, ci = blockIdx.x;
    const float lbr = Lbre[p], lbi = Lbim[p];
    float sr = carR[ci * P_DIM + p];
    float si = carI[ci * P_DIM + p];
    const int t0 = ci * CLEN;
    for (int t = t0; t < t0 + CLEN; ++t) {
        int rs = resets[t];
        float bur = Bu[(size_t)t * 512 + p];
        float bui = Bu[(size_t)t * 512 + 256 + p];
        if (rs) { sr = bur; si = bui; }
        else {
            float nr = lbr * sr - lbi * si + bur;
            si = lbr * si + lbi * sr + bui;
            sr = nr;
        }
        xcu[(size_t)t * 256 + p] = pk(sr, si);
    }
}

// ---------------------------------------------------------------------------
extern "C" void kernel_launch(void* const* d_in, const int* in_sizes, int n_in,
                              void* d_out, int out_size, void* d_ws, size_t ws_size,
                              hipStream_t stream)
{
    const float* hidden  = (const float*)d_in[0];
    const float* u       = (const float*)d_in[1];
    const float* Lre     = (const float*)d_in[2];
    const float* Lim     = (const float*)d_in[3];
    const float* B       = (const float*)d_in[4];
    const float* C       = (const float*)d_in[5];
    const float* D       = (const float*)d_in[6];
    const float* logstep = (const float*)d_in[7];
    const int*   resets  = (const int*)d_in[8];
    float* out = (float*)d_out;
    float* ws  = (float*)d_ws;

    short*    BmT  = (short*)(ws + OFF_BMT);
    short*    W2T  = (short*)(ws + OFF_W2T);
    unsigned* W2Tu = (unsigned*)(ws + OFF_W2T);
    float*    Lbre = ws + OFF_LBRE;
    float*    Lbim = ws + OFF_LBIM;
    float*    Bu   = ws + OFF_BU;
    short*    xc   = (short*)(ws + OFF_XC);
    unsigned* xcu  = (unsigned*)(ws + OFF_XC);

    s5_k0<<<512, 256, 0, stream>>>(Lre, Lim, logstep, B, C, BmT, W2Tu, Lbre, Lbim);

    // GEMM1: Bu = u @ BmT^T   (A fp32 -> bf16 on the fly)
    s5_gemm<true, false><<<dim3(N2P / 64, L_LEN / 64), 256, 0, stream>>>(
        (const void*)u, BmT, nullptr, nullptr, Bu);

    s5_k2<<<CHUNKS, P_DIM, 0, stream>>>(Bu, resets, Lbre, Lbim,
        ws + OFF_AGAR, ws + OFF_AGAI, ws + OFF_AGBR, ws + OFF_AGBI, ws + OFF_AGC);

    s5_k3<<<1, P_DIM, 0, stream>>>(hidden,
        ws + OFF_AGAR, ws + OFF_AGAI, ws + OFF_AGBR, ws + OFF_AGBI, ws + OFF_AGC,
        ws + OFF_CARR, ws + OFF_CARI);

    s5_k4<<<CHUNKS, P_DIM, 0, stream>>>(Bu, resets, Lbre, Lbim,
        ws + OFF_CARR, ws + OFF_CARI, xcu);

    // GEMM2: out = xc @ W2T^T + u*D   (A bf16)
    s5_gemm<false, true><<<dim3(H_DIM / 64, L_LEN / 64), 256, 0, stream>>>(
        (const void*)xc, W2T, u, D, out);
}

// Round 4
// 68.991 us; speedup vs baseline: 3.2021x; 1.8946x over previous
//
#include <hip/hip_runtime.h>

#define L_LEN 8192
#define H_DIM 512
#define P_DIM 256
#define N2P   512
#define CHUNKS 512
#define CLEN  (L_LEN / CHUNKS)

typedef short bf16x8 __attribute__((ext_vector_type(8)));
typedef float f32x4  __attribute__((ext_vector_type(4)));

// ---- workspace layout (FLOAT offsets; bf16 buffers sized as shorts/2) ----
#define OFF_BMT   0                          // bf16 [512][512] -> 131072 floats
#define OFF_W2T   (OFF_BMT + 131072)         // bf16 [512][512] -> 131072 floats
#define OFF_LBRE  (OFF_W2T + 131072)
#define OFF_LBIM  (OFF_LBRE + 256)
#define OFF_BU    (OFF_LBIM + 256)           // fp32 [L][512]
#define OFF_XC    (OFF_BU + L_LEN * 512)     // bf16 [L][512] -> L*256 floats
#define OFF_AGAR  (OFF_XC + L_LEN * 256)
#define OFF_AGAI  (OFF_AGAR + CHUNKS * P_DIM)
#define OFF_AGBR  (OFF_AGAI + CHUNKS * P_DIM)
#define OFF_AGBI  (OFF_AGBR + CHUNKS * P_DIM)
#define OFF_AGC   (OFF_AGBI + CHUNKS * P_DIM)
#define OFF_CARR  (OFF_AGC  + CHUNKS)
#define OFF_CARI  (OFF_CARR + CHUNKS * P_DIM)

__device__ __forceinline__ unsigned short bfr(float x) {
    unsigned u = __float_as_uint(x);
    u = (u + 0x7fffu + ((u >> 16) & 1u)) >> 16;
    return (unsigned short)u;
}
__device__ __forceinline__ unsigned pk(float a, float b) {
    return (unsigned)bfr(a) | ((unsigned)bfr(b) << 16);
}

// ---------------------------------------------------------------------------
// K0: precompute Lambda_bar, BmT (bf16, [2P][H]), W2T (bf16, [H][2P] interleaved)
// ---------------------------------------------------------------------------
__global__ __launch_bounds__(256) void s5_k0(
    const float* __restrict__ Lre, const float* __restrict__ Lim,
    const float* __restrict__ logstep,
    const float* __restrict__ B,   // (P,H,2)
    const float* __restrict__ C,   // (H,P,2)
    short* __restrict__ BmT, unsigned* __restrict__ W2Tu,
    float* __restrict__ Lbre, float* __restrict__ Lbim)
{
    int idx = blockIdx.x * 256 + threadIdx.x;   // 0 .. 131071

    // ---- B_bar part: idx -> (p, h) ----
    int p = idx >> 9, h = idx & 511;
    float lre = Lre[p], lim = Lim[p];
    float s = expf(logstep[p]);
    float er = expf(lre * s);
    float lbr = er * cosf(lim * s);
    float lbi = er * sinf(lim * s);
    if (h == 0) { Lbre[p] = lbr; Lbim[p] = lbi; }
    float nr = lbr - 1.0f, ni = lbi;
    float inv = 1.0f / (lre * lre + lim * lim);
    float fr = (nr * lre + ni * lim) * inv;
    float fi = (ni * lre - nr * lim) * inv;
    float b0 = B[2 * idx + 0];
    float b1 = B[2 * idx + 1];
    BmT[(size_t)p * 512 + h]         = (short)bfr(fr * b0 - fi * b1);
    BmT[(size_t)(256 + p) * 512 + h] = (short)bfr(fr * b1 + fi * b0);

    // ---- C part: idx -> (hh, pp) ----
    int hh = idx >> 8, pp = idx & 255;
    float cre = C[2 * idx + 0];
    float cim = C[2 * idx + 1];
    W2Tu[(size_t)hh * 256 + pp] = pk(2.0f * cre, -2.0f * cim);
}

// ---------------------------------------------------------------------------
// bf16 MFMA GEMM: Out[M=8192][N] = A[M][512] @ WT[N][512]^T (WT row-major [n][k])
// BM=BN=BK=64, 256 threads (4 waves, 2x2), double-buffered padded LDS
// ---------------------------------------------------------------------------
template<bool AFP32, bool EPI>
__global__ __launch_bounds__(256) void s5_gemm(
    const void* __restrict__ Ap, const short* __restrict__ WT,
    const float* __restrict__ u, const float* __restrict__ Dv,
    float* __restrict__ Out)
{
    __shared__ __align__(16) short lds[2][2][64][72];

    const int tid = threadIdx.x;
    const int rowBase = blockIdx.y * 64;
    const int colBase = blockIdx.x * 64;
    const int srow = tid >> 2;
    const int scq  = (tid & 3) * 16;

    const int w = tid >> 6, l = tid & 63;
    const int wr = (w >> 1) * 32, wc = (w & 1) * 32;
    const int fr = l & 15, fq = l >> 4;

    int4 ra0, ra1, rb0, rb1;

    auto LOAD = [&](int t) {
        const int kk = t * 64;
        if (AFP32) {
            const float* A = (const float*)Ap;
            const float4* sa = (const float4*)(A + (size_t)(rowBase + srow) * 512 + kk + scq);
            float4 f0 = sa[0], f1 = sa[1], f2 = sa[2], f3 = sa[3];
            ra0 = make_int4((int)pk(f0.x,f0.y), (int)pk(f0.z,f0.w), (int)pk(f1.x,f1.y), (int)pk(f1.z,f1.w));
            ra1 = make_int4((int)pk(f2.x,f2.y), (int)pk(f2.z,f2.w), (int)pk(f3.x,f3.y), (int)pk(f3.z,f3.w));
        } else {
            const short* A = (const short*)Ap;
            const int4* sa = (const int4*)(A + (size_t)(rowBase + srow) * 512 + kk + scq);
            ra0 = sa[0]; ra1 = sa[1];
        }
        const int4* sb = (const int4*)(WT + (size_t)(colBase + srow) * 512 + kk + scq);
        rb0 = sb[0]; rb1 = sb[1];
    };
    auto WRITE = [&](int buf) {
        *(int4*)&lds[buf][0][srow][scq]     = ra0;
        *(int4*)&lds[buf][0][srow][scq + 8] = ra1;
        *(int4*)&lds[buf][1][srow][scq]     = rb0;
        *(int4*)&lds[buf][1][srow][scq + 8] = rb1;
    };

    f32x4 acc[2][2] = {};

    auto COMPUTE = [&](int buf) {
        #pragma unroll
        for (int kc = 0; kc < 2; ++kc) {
            bf16x8 a0 = *(const bf16x8*)&lds[buf][0][wr +      fr][kc * 32 + 8 * fq];
            bf16x8 a1 = *(const bf16x8*)&lds[buf][0][wr + 16 + fr][kc * 32 + 8 * fq];
            bf16x8 b0 = *(const bf16x8*)&lds[buf][1][wc +      fr][kc * 32 + 8 * fq];
            bf16x8 b1 = *(const bf16x8*)&lds[buf][1][wc + 16 + fr][kc * 32 + 8 * fq];
            acc[0][0] = __builtin_amdgcn_mfma_f32_16x16x32_bf16(a0, b0, acc[0][0], 0, 0, 0);
            acc[0][1] = __builtin_amdgcn_mfma_f32_16x16x32_bf16(a0, b1, acc[0][1], 0, 0, 0);
            acc[1][0] = __builtin_amdgcn_mfma_f32_16x16x32_bf16(a1, b0, acc[1][0], 0, 0, 0);
            acc[1][1] = __builtin_amdgcn_mfma_f32_16x16x32_bf16(a1, b1, acc[1][1], 0, 0, 0);
        }
    };

    LOAD(0); WRITE(0); __syncthreads();
    #pragma unroll
    for (int t = 0; t < 8; ++t) {
        if (t + 1 < 8) LOAD(t + 1);
        COMPUTE(t & 1);
        if (t + 1 < 8) WRITE((t + 1) & 1);
        __syncthreads();
    }

    float dv0 = 0.f, dv1 = 0.f;
    if (EPI) { dv0 = Dv[colBase + wc + fr]; dv1 = Dv[colBase + wc + 16 + fr]; }

    #pragma unroll
    for (int i = 0; i < 2; ++i)
        #pragma unroll
        for (int j = 0; j < 2; ++j)
            #pragma unroll
            for (int q = 0; q < 4; ++q) {
                int r = rowBase + wr + 16 * i + fq * 4 + q;
                int c = colBase + wc + 16 * j + fr;
                float v = acc[i][j][q];
                if (EPI) v += u[(size_t)r * 512 + c] * (j ? dv1 : dv0);
                Out[(size_t)r * 512 + c] = v;
            }
}

// ---------------------------------------------------------------------------
// K2: per-chunk aggregates
// ---------------------------------------------------------------------------
__global__ __launch_bounds__(P_DIM) void s5_k2(
    const float* __restrict__ Bu, const int* __restrict__ resets,
    const float* __restrict__ Lbre, const float* __restrict__ Lbim,
    float* __restrict__ aAr, float* __restrict__ aAi,
    float* __restrict__ aBr, float* __restrict__ aBi, float* __restrict__ aC)
{
    const int p = threadIdx.x, ci = blockIdx.x;
    const float lbr = Lbre[p], lbi = Lbim[p];
    float Ar = 1.f, Ai = 0.f, br = 0.f, bi = 0.f;
    int c = 0;
    const int t0 = ci * CLEN;
    for (int t = t0; t < t0 + CLEN; ++t) {
        int rs = resets[t];
        float bur = Bu[(size_t)t * 512 + p];
        float bui = Bu[(size_t)t * 512 + 256 + p];
        if (rs) { Ar = lbr; Ai = lbi; br = bur; bi = bui; c = 1; }
        else {
            float nAr = lbr * Ar - lbi * Ai; Ai = lbr * Ai + lbi * Ar; Ar = nAr;
            float nbr = lbr * br - lbi * bi + bur; bi = lbr * bi + lbi * br + bui; br = nbr;
        }
    }
    aAr[ci * P_DIM + p] = Ar; aAi[ci * P_DIM + p] = Ai;
    aBr[ci * P_DIM + p] = br; aBi[ci * P_DIM + p] = bi;
    if (p == 0) aC[ci] = (float)c;
}

// ---------------------------------------------------------------------------
// K3p: parallel scan over chunk aggregates -> carry-in per chunk
// grid = P_DIM blocks (one per channel p), CHUNKS threads (one per chunk)
// Hillis-Steele inclusive scan with the reset-composition operator.
// ---------------------------------------------------------------------------
__global__ __launch_bounds__(CHUNKS) void s5_k3p(
    const float* __restrict__ hidden,
    const float* __restrict__ aAr, const float* __restrict__ aAi,
    const float* __restrict__ aBr, const float* __restrict__ aBi,
    const float* __restrict__ aC,
    float* __restrict__ carR, float* __restrict__ carI)
{
    __shared__ float sAr[CHUNKS], sAi[CHUNKS], sBr[CHUNKS], sBi[CHUNKS], sC[CHUNKS];
    const int p = blockIdx.x, t = threadIdx.x;

    float Ar = aAr[t * P_DIM + p], Ai = aAi[t * P_DIM + p];
    float br = aBr[t * P_DIM + p], bi = aBi[t * P_DIM + p];
    float c  = aC[t];
    sAr[t] = Ar; sAi[t] = Ai; sBr[t] = br; sBi[t] = bi; sC[t] = c;
    __syncthreads();

    for (int s = 1; s < CHUNKS; s <<= 1) {
        float pAr = 0.f, pAi = 0.f, pBr = 0.f, pBi = 0.f, pC = 0.f;
        const bool has = (t >= s);
        if (has) { pAr = sAr[t-s]; pAi = sAi[t-s]; pBr = sBr[t-s]; pBi = sBi[t-s]; pC = sC[t-s]; }
        __syncthreads();
        if (has) {
            if (c <= 0.5f) {   // current segment has no reset: compose with earlier
                float nAr = Ar * pAr - Ai * pAi;
                float nAi = Ar * pAi + Ai * pAr;
                float nbr = Ar * pBr - Ai * pBi + br;
                float nbi = Ar * pBi + Ai * pBr + bi;
                Ar = nAr; Ai = nAi; br = nbr; bi = nbi; c = pC;
            }                  // else: reset inside current segment -> unchanged
            sAr[t] = Ar; sAi[t] = Ai; sBr[t] = br; sBi[t] = bi; sC[t] = c;
        }
        __syncthreads();
    }

    // carry for chunk t = inclusive[t-1] applied to (hidden, 0); chunk 0 = hidden
    const float h = hidden[p];
    float sr, si;
    if (t == 0) { sr = h; si = 0.f; }
    else {
        float gAr = sAr[t-1], gAi = sAi[t-1], gBr = sBr[t-1], gBi = sBi[t-1], gC = sC[t-1];
        if (gC > 0.5f) { sr = gBr; si = gBi; }
        else           { sr = gAr * h + gBr; si = gAi * h + gBi; }
    }
    carR[t * P_DIM + p] = sr;
    carI[t * P_DIM + p] = si;
}

// ---------------------------------------------------------------------------
// K4: re-scan with carry, write xs as packed bf16 (re,im) per p
// ---------------------------------------------------------------------------
__global__ __launch_bounds__(P_DIM) void s5_k4(
    const float* __restrict__ Bu, const int* __restrict__ resets,
    const float* __restrict__ Lbre, const float* __restrict__ Lbim,
    const float* __restrict__ carR, const float* __restrict__ carI,
    unsigned* __restrict__ xcu)
{
    const int p = threadIdx.x, ci = blockIdx.x;
    const float lbr = Lbre[p], lbi = Lbim[p];
    float sr = carR[ci * P_DIM + p];
    float si = carI[ci * P_DIM + p];
    const int t0 = ci * CLEN;
    for (int t = t0; t < t0 + CLEN; ++t) {
        int rs = resets[t];
        float bur = Bu[(size_t)t * 512 + p];
        float bui = Bu[(size_t)t * 512 + 256 + p];
        if (rs) { sr = bur; si = bui; }
        else {
            float nr = lbr * sr - lbi * si + bur;
            si = lbr * si + lbi * sr + bui;
            sr = nr;
        }
        xcu[(size_t)t * 256 + p] = pk(sr, si);
    }
}

// ---------------------------------------------------------------------------
extern "C" void kernel_launch(void* const* d_in, const int* in_sizes, int n_in,
                              void* d_out, int out_size, void* d_ws, size_t ws_size,
                              hipStream_t stream)
{
    const float* hidden  = (const float*)d_in[0];
    const float* u       = (const float*)d_in[1];
    const float* Lre     = (const float*)d_in[2];
    const float* Lim     = (const float*)d_in[3];
    const float* B       = (const float*)d_in[4];
    const float* C       = (const float*)d_in[5];
    const float* D       = (const float*)d_in[6];
    const float* logstep = (const float*)d_in[7];
    const int*   resets  = (const int*)d_in[8];
    float* out = (float*)d_out;
    float* ws  = (float*)d_ws;

    short*    BmT  = (short*)(ws + OFF_BMT);
    short*    W2T  = (short*)(ws + OFF_W2T);
    unsigned* W2Tu = (unsigned*)(ws + OFF_W2T);
    float*    Lbre = ws + OFF_LBRE;
    float*    Lbim = ws + OFF_LBIM;
    float*    Bu   = ws + OFF_BU;
    short*    xc   = (short*)(ws + OFF_XC);
    unsigned* xcu  = (unsigned*)(ws + OFF_XC);

    s5_k0<<<512, 256, 0, stream>>>(Lre, Lim, logstep, B, C, BmT, W2Tu, Lbre, Lbim);

    // GEMM1: Bu = u @ BmT^T   (A fp32 -> bf16 on the fly)
    s5_gemm<true, false><<<dim3(N2P / 64, L_LEN / 64), 256, 0, stream>>>(
        (const void*)u, BmT, nullptr, nullptr, Bu);

    s5_k2<<<CHUNKS, P_DIM, 0, stream>>>(Bu, resets, Lbre, Lbim,
        ws + OFF_AGAR, ws + OFF_AGAI, ws + OFF_AGBR, ws + OFF_AGBI, ws + OFF_AGC);

    s5_k3p<<<P_DIM, CHUNKS, 0, stream>>>(hidden,
        ws + OFF_AGAR, ws + OFF_AGAI, ws + OFF_AGBR, ws + OFF_AGBI, ws + OFF_AGC,
        ws + OFF_CARR, ws + OFF_CARI);

    s5_k4<<<CHUNKS, P_DIM, 0, stream>>>(Bu, resets, Lbre, Lbim,
        ws + OFF_CARR, ws + OFF_CARI, xcu);

    // GEMM2: out = xc @ W2T^T + u*D   (A bf16)
    s5_gemm<false, true><<<dim3(H_DIM / 64, L_LEN / 64), 256, 0, stream>>>(
        (const void*)xc, W2T, u, D, out);
}